// Round 11
// baseline (474.007 us; speedup 1.0000x reference)
//
#include <hip/hip_runtime.h>
#include <hip/hip_bf16.h>

typedef short short8 __attribute__((ext_vector_type(8)));
typedef float f32x4 __attribute__((ext_vector_type(4)));
typedef float f32x16 __attribute__((ext_vector_type(16)));
typedef unsigned short u16;
typedef unsigned short u16x4 __attribute__((ext_vector_type(4)));

__device__ __forceinline__ u16 f2bf(float f) {
  __hip_bfloat16 h = __float2bfloat16(f);
  return __builtin_bit_cast(u16, h);
}
__device__ __forceinline__ float bf2f(u16 u) {
  return __bfloat162float(__builtin_bit_cast(__hip_bfloat16, u));
}
__device__ __forceinline__ void gload_lds16(const void* g, void* l) {
  __builtin_amdgcn_global_load_lds(
      (const __attribute__((address_space(1))) void*)g,
      (__attribute__((address_space(3))) void*)l, 16, 0, 0);
}
__device__ __forceinline__ unsigned cvtpk(float lo, float hi) {
  unsigned r;
  asm("v_cvt_pk_bf16_f32 %0, %1, %2" : "=v"(r) : "v"(lo), "v"(hi));
  return r;
}

// ---------------- lens from padding mask (auto-detect bool vs int32 layout) ----
__global__ void compute_lens(const unsigned char* __restrict__ mask, int* __restrict__ lens) {
  __shared__ int flag;
  __shared__ int cnt[4];
  const int tid = threadIdx.x;
  if (tid == 0) flag = 0;
  if (tid < 4) cnt[tid] = 0;
  __syncthreads();
  int found = 0;
  for (int i = tid; i < 8192; i += 256)
    if (mask[i] == 1 && (i & 3) != 0) found = 1;
  if (found) atomicOr(&flag, 1);
  __syncthreads();
  int l0 = 0, l1 = 0, l2 = 0, l3 = 0;
  if (flag) {
    for (int i = tid; i < 8192; i += 256) {
      int z = (mask[i] == 0);
      int b = i >> 11;
      l0 += z & (b == 0); l1 += z & (b == 1); l2 += z & (b == 2); l3 += z & (b == 3);
    }
  } else {
    const int* mi = (const int*)mask;
    for (int i = tid; i < 8192; i += 256) {
      int z = (mi[i] == 0);
      int b = i >> 11;
      l0 += z & (b == 0); l1 += z & (b == 1); l2 += z & (b == 2); l3 += z & (b == 3);
    }
  }
  if (l0) atomicAdd(&cnt[0], l0);
  if (l1) atomicAdd(&cnt[1], l1);
  if (l2) atomicAdd(&cnt[2], l2);
  if (l3) atomicAdd(&cnt[3], l3);
  __syncthreads();
  if (tid < 4) lens[tid] = cnt[tid];
}

// ---------------- weight convert f32[K][N] -> bf16[N][K] (transpose) ----------
// ilv: 0 = identity row map; 1/2 = interleave W1/V1 into combined FF1 matrix
__global__ void convT(const float* __restrict__ in, u16* __restrict__ out,
                      int K, int N, long inz, long outz, int ilv) {
  __shared__ float t[32][33];
  const int n0 = blockIdx.x * 32, k0 = blockIdx.y * 32;
  const float* ip = in + (size_t)blockIdx.z * inz;
  u16* op = out + (size_t)blockIdx.z * outz;
  const int tx = threadIdx.x & 31, ty = threadIdx.x >> 5;
  for (int i = ty; i < 32; i += 8)
    t[i][tx] = ip[(size_t)(k0 + i) * N + n0 + tx];
  __syncthreads();
  for (int i = ty; i < 32; i += 8) {
    const int rn = n0 + i;
    const int r = ilv ? ((((rn >> 4) << 5) | (rn & 15)) | ((ilv - 1) << 4)) : rn;
    op[(size_t)r * K + k0 + tx] = f2bf(t[tx][i]);
  }
}

// ---------------- RMSNorm: f32 [row][1024] -> bf16 --------------------------
__global__ void rmsnorm_kernel(const float* __restrict__ in, const float* __restrict__ g,
                               u16* __restrict__ out) {
  __shared__ float psum[4];
  const int row = blockIdx.x, tid = threadIdx.x;
  const float4 x = ((const float4*)(in + (size_t)row * 1024))[tid];
  float ss = x.x * x.x + x.y * x.y + x.z * x.z + x.w * x.w;
  for (int m = 1; m < 64; m <<= 1) ss += __shfl_xor(ss, m, 64);
  if ((tid & 63) == 0) psum[tid >> 6] = ss;
  __syncthreads();
  const float tot = psum[0] + psum[1] + psum[2] + psum[3];
  const float inv = rsqrtf(tot * (1.0f / 1024.0f));
  const float4 gv = ((const float4*)g)[tid];
  u16x4 o;
  o[0] = f2bf(gv.x * x.x * inv); o[1] = f2bf(gv.y * x.y * inv);
  o[2] = f2bf(gv.z * x.z * inv); o[3] = f2bf(gv.w * x.w * inv);
  *(u16x4*)&out[(size_t)row * 1024 + tid * 4] = o;
}

// ---------------- 2-blocks/CU phase-pipelined bf16 GEMM ----------------------
// BN=256 always, 8 waves (2x4). Two shapes:
//  BM=128, BK=32: LDS 48KB, VGPR~110 -> 2 blocks/CU (cross-block overlap).
//  BM=64,  BK=64: LDS 80KB -> 2 blocks/CU (for N=1024 outputs, grid 512).
// R6-proven 2-phase schedule: entry vmcnt(1)+barrier; P0 stage B(t+1)->c^1,
// read all frags, MFMA ni01; barrier; P1 stage A(t+2)->c, MFMA ni23.
enum { MQKV = 0, MSA = 1, MFSILU = 2, MFF2 = 3 };

template <int MODE, int BM>
__global__ __launch_bounds__(512, 4) void gemm4(
    const u16* __restrict__ A, const u16* __restrict__ Bt,
    const int K,
    u16* __restrict__ oq, u16* __restrict__ ok, u16* __restrict__ ov,
    float* __restrict__ of, const float* __restrict__ afp,
    u16* __restrict__ ob) {
  constexpr int BK = (BM == 128) ? 32 : 64;
  constexpr int KS = BK / 32;          // 16x16x32 steps per tile (1 or 2)
  constexpr int MR = BM / 32;          // per-wave mi frags (4 or 2)
  constexpr int ABUF = BM * BK;        // = 4096 u16 both shapes
  constexpr int BBUF = 256 * BK;       // u16
  constexpr int CPR = BK / 8;          // 16B chunks per row
  constexpr int BIT = BBUF / 4096;     // B glds iters (2 or 4)
  __shared__ u16 lds[2 * ABUF + 2 * BBUF];
  const int tid = threadIdx.x;
  const int w = tid >> 6, l = tid & 63;
  const int wr = w >> 2, wc = w & 3;
  const int lane16 = l & 15, lgrp = l >> 4;

  // 2D supertile XCD mapping (bijective per grid)
  const int bid = (int)blockIdx.x, xcd = bid & 7, seq = bid >> 3;
  int by, bx;
  if (MODE == MQKV) {            // BM=128: MT=64, NT=12, grid 768
    const int j = seq / 24, t5 = seq % 24;
    by = (xcd >> 2) * 32 + j * 8 + t5 / 3;
    bx = (xcd & 3) * 3 + t5 % 3;
  } else if (MODE == MFSILU) {   // BM=128: MT=64, NT=32, grid 2048
    by = seq >> 2;
    bx = xcd * 4 + (seq & 3);
  } else {                        // BM=64: MT=128, NT=4, grid 512
    by = (xcd >> 1) * 32 + (seq >> 1);
    bx = (xcd & 1) * 2 + (seq & 1);
  }
  const int row0 = by * BM, col0 = bx * 256;

  auto swz = [](int r) -> int {
    if (BK == 64) return r & 7;
    return (r & 3) ^ ((r >> 2) & 3);
  };
  auto stageA = [&](int kt, int buf) {   // 512 chunks = 1 glds/thread
    const int r = tid / CPR, j = (tid % CPR) ^ swz(r);
    gload_lds16(A + (size_t)(row0 + r) * K + kt * BK + j * 8,
                &lds[buf * ABUF + tid * 8]);
  };
  auto stageB = [&](int kt, int buf) {
#pragma unroll
    for (int i = 0; i < BIT; ++i) {
      const int cc = i * 512 + tid;
      const int r = cc / CPR, j = (cc % CPR) ^ swz(r);
      gload_lds16(Bt + (size_t)(col0 + r) * K + kt * BK + j * 8,
                  &lds[2 * ABUF + buf * BBUF + cc * 8]);
    }
  };
  auto frofs = [&](int rrow, int ks) {   // u16 offset of a frag
    const int chunk = ((KS == 2 ? ks * 4 + lgrp : lgrp)) ^ swz(rrow);
    return rrow * BK + chunk * 8;
  };

  f32x4 zero = {0.f, 0.f, 0.f, 0.f};
  f32x4 acc[MR][4];
#pragma unroll
  for (int i = 0; i < MR; ++i)
#pragma unroll
    for (int j = 0; j < 4; ++j) acc[i][j] = zero;

  const int nkt = K / BK;
  stageA(0, 0); stageB(0, 0); stageA(1, 1);

  for (int t = 0; t < nkt; ++t) {
    const int c = t & 1;
    if (t == nkt - 1)  asm volatile("s_waitcnt vmcnt(0)\ns_barrier" ::: "memory");
    else               asm volatile("s_waitcnt vmcnt(1)\ns_barrier" ::: "memory");
    const u16* ap = &lds[c * ABUF];
    const u16* bp = &lds[2 * ABUF + c * BBUF];
    short8 a[MR][KS], b01[2][KS], b23[2][KS];

    // ---- P0: stage B(t+1)->c^1, read all frags, MFMA x ni01 ----
    if (t + 1 < nkt) stageB(t + 1, c ^ 1);
#pragma unroll
    for (int mi = 0; mi < MR; ++mi)
#pragma unroll
      for (int ks = 0; ks < KS; ++ks)
        a[mi][ks] = *(const short8*)&ap[frofs(wr * (BM / 2) + mi * 16 + lane16, ks)];
#pragma unroll
    for (int ni = 0; ni < 2; ++ni)
#pragma unroll
      for (int ks = 0; ks < KS; ++ks) {
        b01[ni][ks] = *(const short8*)&bp[frofs(wc * 64 + ni * 16 + lane16, ks)];
        b23[ni][ks] = *(const short8*)&bp[frofs(wc * 64 + (ni + 2) * 16 + lane16, ks)];
      }
    __builtin_amdgcn_s_setprio(1);
#pragma unroll
    for (int ks = 0; ks < KS; ++ks)
#pragma unroll
      for (int mi = 0; mi < MR; ++mi)
#pragma unroll
        for (int ni = 0; ni < 2; ++ni)
          acc[mi][ni] = __builtin_amdgcn_mfma_f32_16x16x32_bf16(a[mi][ks], b01[ni][ks], acc[mi][ni], 0, 0, 0);
    __builtin_amdgcn_s_setprio(0);
    asm volatile("s_waitcnt lgkmcnt(0)" ::: "memory");
    asm volatile("s_barrier" ::: "memory");

    // ---- P1: stage A(t+2)->c (A(c) reads retired), MFMA x ni23 ----
    if (t + 2 < nkt) stageA(t + 2, c);
    __builtin_amdgcn_s_setprio(1);
#pragma unroll
    for (int ks = 0; ks < KS; ++ks)
#pragma unroll
      for (int mi = 0; mi < MR; ++mi)
#pragma unroll
        for (int ni = 0; ni < 2; ++ni)
          acc[mi][ni + 2] = __builtin_amdgcn_mfma_f32_16x16x32_bf16(a[mi][ks], b23[ni][ks], acc[mi][ni + 2], 0, 0, 0);
    __builtin_amdgcn_s_setprio(0);
  }
  asm volatile("s_barrier" ::: "memory");

  // ---------------- epilogues ----------------
  if (MODE == MQKV) {
#pragma unroll
    for (int mi = 0; mi < MR; ++mi) {
      const int sbase = row0 + wr * (BM / 2) + mi * 16 + lgrp * 4;
      const int bbt = sbase >> 11, sr = sbase & 2047;
#pragma unroll
      for (int ni = 0; ni < 4; ++ni) {
        const int j = col0 + wc * 64 + ni * 16 + lane16;
        const int which = j >> 10, rr = j & 1023, h = rr >> 6, kk = rr & 63;
        const int bh = bbt * 16 + h;
        if (which == 2) {
          u16x4 pk;
#pragma unroll
          for (int r = 0; r < 4; ++r) pk[r] = f2bf(acc[mi][ni][r]);
          *(u16x4*)&ov[((size_t)bh * 64 + kk) * 2048 + sr] = pk;  // V^T [bh][dk][t]
        } else {
          u16* dst = (which == 0) ? oq : ok;
          const float scl = (which == 0) ? 0.125f : 1.0f;
#pragma unroll
          for (int r = 0; r < 4; ++r)
            dst[((size_t)bh * 2048 + sr + r) * 64 + kk] = f2bf(acc[mi][ni][r] * scl);
        }
      }
    }
  } else if (MODE == MFSILU) {
    // fused FF1: even ni fragments = h1 (W1), odd = h2 (V1); out = silu(h1)*h2
    u16* ep = &lds[w * 576];  // per-wave [16][34] overlay (A-buf region only)
    const int orow = l >> 2, ocol = (l & 3) * 8;
#pragma unroll
    for (int mi = 0; mi < MR; ++mi) {
#pragma unroll
      for (int p = 0; p < 2; ++p)
#pragma unroll
        for (int r = 0; r < 4; ++r) {
          const float h1 = acc[mi][2 * p][r], h2 = acc[mi][2 * p + 1][r];
          ep[(lgrp * 4 + r) * 34 + p * 16 + lane16] = f2bf(h1 / (1.0f + __expf(-h1)) * h2);
        }
      short8 v = *(const short8*)&ep[orow * 34 + ocol];
      *(short8*)&ob[(size_t)(row0 + wr * (BM / 2) + mi * 16 + orow) * 4096 +
                    (col0 >> 1) + wc * 32 + ocol] = v;
    }
  } else {  // MSA / MFF2: f32 out with residual / accumulate (N = 1024)
#pragma unroll
    for (int mi = 0; mi < MR; ++mi) {
      const int row = row0 + wr * (BM / 2) + mi * 16 + lgrp * 4;
#pragma unroll
      for (int ni = 0; ni < 4; ++ni) {
        const int j = col0 + wc * 64 + ni * 16 + lane16;
#pragma unroll
        for (int r = 0; r < 4; ++r) {
          const size_t idx = (size_t)(row + r) * 1024 + j;
          const float base = (MODE == MSA) ? afp[idx] : of[idx];
          of[idx] = base + acc[mi][ni][r];
        }
      }
    }
  }
}

// ---------------- attention: 4 warps x 32 Q-rows, swapped 32x32 MFMA ---------
__global__ void attn2_kernel(const u16* __restrict__ qb, const u16* __restrict__ kb,
                             const u16* __restrict__ vT, u16* __restrict__ obuf,
                             const int* __restrict__ lens) {
  __shared__ u16 sm[9216];
  const int tid = threadIdx.x;
  const int l = tid & 63, wid = tid >> 6;
  const int l31 = l & 31, hi = l >> 5;
  const int bh = blockIdx.x, b = bh >> 4, h = bh & 15;
  const int q0 = blockIdx.y * 128;
  const int len = lens[b];

  if (q0 >= len) {
    short8 z = {0, 0, 0, 0, 0, 0, 0, 0};
#pragma unroll
    for (int c = 0; c < 4; ++c) {
      const int ck = c * 256 + tid;
      const int r = ck >> 3, j = ck & 7;
      *(short8*)&obuf[((size_t)b * 2048 + q0 + r) * 1024 + h * 64 + j * 8] = z;
    }
    return;
  }

  const int q0w = q0 + wid * 32;
  const u16* qp = qb + ((size_t)bh * 2048 + q0w + l31) * 64;
  short8 qf0 = *(const short8*)(qp + hi * 8);
  short8 qf1 = *(const short8*)(qp + 16 + hi * 8);
  short8 qf2 = *(const short8*)(qp + 32 + hi * 8);
  short8 qf3 = *(const short8*)(qp + 48 + hi * 8);

  f32x16 oa0 = {0.f,0.f,0.f,0.f,0.f,0.f,0.f,0.f,0.f,0.f,0.f,0.f,0.f,0.f,0.f,0.f};
  f32x16 oa1 = oa0;
  float m_run = -1e30f, l_run = 0.f;

  const int swz = (l31 & 7) << 3;
  const int nt = (len + 63) >> 6;
  for (int kt = 0; kt < nt; ++kt) {
    const int t0 = kt * 64;
    __syncthreads();
#pragma unroll
    for (int c = 0; c < 2; ++c) {
      const int ck = c * 256 + wid * 64 + l;
      const int r = ck >> 3;
      const int j = (ck & 7) ^ (r & 7);
      gload_lds16(kb + ((size_t)bh * 2048 + t0 + r) * 64 + j * 8,
                  &sm[(c * 256 + wid * 64) * 8]);
      gload_lds16(vT + ((size_t)bh * 64 + r) * 2048 + t0 + j * 8,
                  &sm[4096 + (c * 256 + wid * 64) * 8]);
    }
    __syncthreads();

    f32x16 sc0 = {0.f,0.f,0.f,0.f,0.f,0.f,0.f,0.f,0.f,0.f,0.f,0.f,0.f,0.f,0.f,0.f};
    f32x16 sc1 = sc0;
#pragma unroll
    for (int ds = 0; ds < 4; ++ds) {
      const int col = (ds * 16 + hi * 8) ^ swz;
      const short8 kf0 = *(const short8*)&sm[(0 + l31) * 64 + col];
      const short8 kf1 = *(const short8*)&sm[(32 + l31) * 64 + col];
      const short8 qf = (ds == 0) ? qf0 : (ds == 1) ? qf1 : (ds == 2) ? qf2 : qf3;
      sc0 = __builtin_amdgcn_mfma_f32_32x32x16_bf16(kf0, qf, sc0, 0, 0, 0);
      sc1 = __builtin_amdgcn_mfma_f32_32x32x16_bf16(kf1, qf, sc1, 0, 0, 0);
    }

    if (t0 + 64 > len) {
      const int tb = t0 + 4 * hi;
#pragma unroll
      for (int i = 0; i < 16; ++i) {
        const int tg = tb + (i & 3) + 8 * (i >> 2);
        if (tg >= len) sc0[i] = -1e30f;
        if (tg + 32 >= len) sc1[i] = -1e30f;
      }
    }

    float mt = sc0[0];
#pragma unroll
    for (int i = 1; i < 16; ++i) mt = fmaxf(mt, sc0[i]);
#pragma unroll
    for (int i = 0; i < 16; ++i) mt = fmaxf(mt, sc1[i]);
    mt = fmaxf(mt, __shfl_xor(mt, 32, 64));
    const float mnew = fmaxf(m_run, mt);
    const float fac = __expf(m_run - mnew);
    m_run = mnew;
    float sum = 0.f;
#pragma unroll
    for (int i = 0; i < 16; ++i) { sc0[i] = __expf(sc0[i] - mnew); sum += sc0[i]; }
#pragma unroll
    for (int i = 0; i < 16; ++i) { sc1[i] = __expf(sc1[i] - mnew); sum += sc1[i]; }
    sum += __shfl_xor(sum, 32, 64);
    l_run = l_run * fac + sum;
#pragma unroll
    for (int i = 0; i < 16; ++i) { oa0[i] *= fac; oa1[i] *= fac; }

    unsigned wv[16];
#pragma unroll
    for (int k = 0; k < 8; ++k) wv[k] = cvtpk(sc0[2 * k], sc0[2 * k + 1]);
#pragma unroll
    for (int k = 0; k < 8; ++k) wv[8 + k] = cvtpk(sc1[2 * k], sc1[2 * k + 1]);
    unsigned pw[16];
#pragma unroll
    for (int s = 0; s < 2; ++s) {
#pragma unroll
      for (int half = 0; half < 2; ++half) {
        const unsigned a0 = wv[8 * s + 4 * half + 0], a1 = wv[8 * s + 4 * half + 1];
        const unsigned a2 = wv[8 * s + 4 * half + 2], a3 = wv[8 * s + 4 * half + 3];
        const unsigned e0 = (unsigned)__shfl_xor((int)(hi ? a0 : a2), 32, 64);
        const unsigned e1 = (unsigned)__shfl_xor((int)(hi ? a1 : a3), 32, 64);
        const int o = s * 8 + half * 4;
        pw[o + 0] = hi ? e0 : a0;
        pw[o + 1] = hi ? e1 : a1;
        pw[o + 2] = hi ? a2 : e0;
        pw[o + 3] = hi ? a3 : e1;
      }
    }
#pragma unroll
    for (int g = 0; g < 4; ++g) {
      union { unsigned u[4]; short8 s8; } pk;
      pk.u[0] = pw[4 * g + 0]; pk.u[1] = pw[4 * g + 1];
      pk.u[2] = pw[4 * g + 2]; pk.u[3] = pw[4 * g + 3];
      const int col = (g * 16 + hi * 8) ^ swz;
      const short8 vf0 = *(const short8*)&sm[4096 + (0 + l31) * 64 + col];
      const short8 vf1 = *(const short8*)&sm[4096 + (32 + l31) * 64 + col];
      oa0 = __builtin_amdgcn_mfma_f32_32x32x16_bf16(vf0, pk.s8, oa0, 0, 0, 0);
      oa1 = __builtin_amdgcn_mfma_f32_32x32x16_bf16(vf1, pk.s8, oa1, 0, 0, 0);
    }
  }

  __syncthreads();
  const float invl = 1.0f / l_run;
  u16* ow = &sm[wid * 2304];  // per-warp [32 s][72]
#pragma unroll
  for (int i = 0; i < 16; ++i) {
    const int d0 = (i & 3) + 8 * (i >> 2) + 4 * hi;
    ow[l31 * 72 + d0] = f2bf(oa0[i] * invl);
    ow[l31 * 72 + 32 + d0] = f2bf(oa1[i] * invl);
  }
  short8 z = {0, 0, 0, 0, 0, 0, 0, 0};
#pragma unroll
  for (int c = 0; c < 4; ++c) {
    const int ck = c * 64 + l;
    const int r = ck >> 3, j = ck & 7;
    short8 v = *(const short8*)&ow[r * 72 + j * 8];
    if (q0w + r >= len) v = z;
    *(short8*)&obuf[((size_t)b * 2048 + q0w + r) * 1024 + h * 64 + j * 8] = v;
  }
}

// ---------------- launch ------------------------------------------------------
extern "C" void kernel_launch(void* const* d_in, const int* in_sizes, int n_in,
                              void* d_out, int out_size, void* d_ws, size_t ws_size,
                              hipStream_t stream) {
  const float* src = (const float*)d_in[0];
  const unsigned char* mask = (const unsigned char*)d_in[1];
  const float* Wq = (const float*)d_in[2];
  const float* Wk = (const float*)d_in[3];
  const float* Wv = (const float*)d_in[4];
  const float* Wo = (const float*)d_in[5];
  const float* g1 = (const float*)d_in[6];
  const float* g2 = (const float*)d_in[7];
  const float* W1 = (const float*)d_in[8];
  const float* V1 = (const float*)d_in[9];
  const float* W2 = (const float*)d_in[10];
  float* out = (float*)d_out;
  char* ws = (char*)d_ws;

  int* lens   = (int*)ws;
  u16* WqkvT  = (u16*)(ws + 256);        // [3072][1024]
  u16* WoT    = (u16*)(ws + 6291712);    // [1024][1024]
  u16* W1V1T  = (u16*)(ws + 8388864);    // [8192][1024] interleaved W1|V1
  u16* W2T    = (u16*)(ws + 25166080);   // [1024][4096]
  u16* xb     = (u16*)(ws + 33554688);   // [8192][1024] bf16 (x, later y)
  u16* qbf    = (u16*)(ws + 50331904);   // [64][2048][64] (pre-scaled by 1/8)
  u16* kbf    = (u16*)(ws + 67109120);   // [64][2048][64]
  u16* vTb    = (u16*)(ws + 83886336);   // [64][64][2048]
  u16* obf    = (u16*)(ws + 100663552);  // [8192][1024]
  u16* c1     = qbf;                     // [8192][4096] reuses q|k|vT|o region

  compute_lens<<<1, 256, 0, stream>>>(mask, lens);
  convT<<<dim3(2, 32, 16), 256, 0, stream>>>(Wq, WqkvT, 1024, 64, 65536, 65536, 0);
  convT<<<dim3(2, 32, 16), 256, 0, stream>>>(Wk, WqkvT + 1024 * 1024, 1024, 64, 65536, 65536, 0);
  convT<<<dim3(2, 32, 16), 256, 0, stream>>>(Wv, WqkvT + 2048 * 1024, 1024, 64, 65536, 65536, 0);
  convT<<<dim3(32, 32, 1), 256, 0, stream>>>(Wo, WoT, 1024, 1024, 0, 0, 0);
  convT<<<dim3(128, 32, 1), 256, 0, stream>>>(W1, W1V1T, 1024, 4096, 0, 0, 1);
  convT<<<dim3(128, 32, 1), 256, 0, stream>>>(V1, W1V1T, 1024, 4096, 0, 0, 2);
  convT<<<dim3(32, 128, 1), 256, 0, stream>>>(W2, W2T, 4096, 1024, 0, 0, 0);

  rmsnorm_kernel<<<8192, 256, 0, stream>>>(src, g1, xb);
  gemm4<MQKV, 128><<<768, 512, 0, stream>>>(xb, WqkvT, 1024,
                                            qbf, kbf, vTb, nullptr, nullptr, nullptr);
  attn2_kernel<<<dim3(64, 16), 256, 0, stream>>>(qbf, kbf, vTb, obf, lens);
  gemm4<MSA, 64><<<512, 512, 0, stream>>>(obf, WoT, 1024,
                                          nullptr, nullptr, nullptr, out, src, nullptr);
  rmsnorm_kernel<<<8192, 256, 0, stream>>>(out, g2, xb);
  gemm4<MFSILU, 128><<<2048, 512, 0, stream>>>(xb, W1V1T, 1024,
                                               nullptr, nullptr, nullptr, nullptr, nullptr, c1);
  gemm4<MFF2, 64><<<512, 512, 0, stream>>>(c1, W2T, 4096,
                                           nullptr, nullptr, nullptr, out, nullptr, nullptr);
}

// Round 12
// 446.278 us; speedup vs baseline: 1.0621x; 1.0621x over previous
//
#include <hip/hip_runtime.h>
#include <hip/hip_bf16.h>

typedef short short8 __attribute__((ext_vector_type(8)));
typedef float f32x4 __attribute__((ext_vector_type(4)));
typedef float f32x16 __attribute__((ext_vector_type(16)));
typedef unsigned short u16;
typedef unsigned short u16x4 __attribute__((ext_vector_type(4)));

__device__ __forceinline__ u16 f2bf(float f) {
  __hip_bfloat16 h = __float2bfloat16(f);
  return __builtin_bit_cast(u16, h);
}
__device__ __forceinline__ float bf2f(u16 u) {
  return __bfloat162float(__builtin_bit_cast(__hip_bfloat16, u));
}
__device__ __forceinline__ void gload_lds16(const void* g, void* l) {
  __builtin_amdgcn_global_load_lds(
      (const __attribute__((address_space(1))) void*)g,
      (__attribute__((address_space(3))) void*)l, 16, 0, 0);
}
__device__ __forceinline__ unsigned cvtpk(float lo, float hi) {
  unsigned r;
  asm("v_cvt_pk_bf16_f32 %0, %1, %2" : "=v"(r) : "v"(lo), "v"(hi));
  return r;
}

// ---------------- lens from padding mask (auto-detect bool vs int32 layout) ----
__global__ void compute_lens(const unsigned char* __restrict__ mask, int* __restrict__ lens) {
  __shared__ int flag;
  __shared__ int cnt[4];
  const int tid = threadIdx.x;
  if (tid == 0) flag = 0;
  if (tid < 4) cnt[tid] = 0;
  __syncthreads();
  int found = 0;
  for (int i = tid; i < 8192; i += 256)
    if (mask[i] == 1 && (i & 3) != 0) found = 1;
  if (found) atomicOr(&flag, 1);
  __syncthreads();
  int l0 = 0, l1 = 0, l2 = 0, l3 = 0;
  if (flag) {
    for (int i = tid; i < 8192; i += 256) {
      int z = (mask[i] == 0);
      int b = i >> 11;
      l0 += z & (b == 0); l1 += z & (b == 1); l2 += z & (b == 2); l3 += z & (b == 3);
    }
  } else {
    const int* mi = (const int*)mask;
    for (int i = tid; i < 8192; i += 256) {
      int z = (mi[i] == 0);
      int b = i >> 11;
      l0 += z & (b == 0); l1 += z & (b == 1); l2 += z & (b == 2); l3 += z & (b == 3);
    }
  }
  if (l0) atomicAdd(&cnt[0], l0);
  if (l1) atomicAdd(&cnt[1], l1);
  if (l2) atomicAdd(&cnt[2], l2);
  if (l3) atomicAdd(&cnt[3], l3);
  __syncthreads();
  if (tid < 4) lens[tid] = cnt[tid];
}

// ---------------- fused weight convert: all 7 transposes in one launch -------
// 16384 blocks of 256 threads; blockIdx range selects the job.
__global__ void convT_all(const float* __restrict__ Wq, const float* __restrict__ Wk,
                          const float* __restrict__ Wv, const float* __restrict__ Wo,
                          const float* __restrict__ W1, const float* __restrict__ V1,
                          const float* __restrict__ W2,
                          u16* __restrict__ WqkvT, u16* __restrict__ WoT,
                          u16* __restrict__ W1V1T, u16* __restrict__ W2T) {
  __shared__ float t[32][33];
  int b = (int)blockIdx.x;
  const float* in;
  u16* op;
  int K, N, n0, k0, ilv = 0;
  if (b < 3072) {                       // Wq/Wk/Wv: per-head [1024][64]
    const int which = b >> 10;
    b &= 1023;
    in = (which == 0) ? Wq : (which == 1) ? Wk : Wv;
    const int z = b >> 6;               // head
    in += (size_t)z * 65536;
    op = WqkvT + (size_t)which * 1048576 + (size_t)z * 65536;
    K = 1024; N = 64;
    n0 = (b & 1) * 32; k0 = ((b >> 1) & 31) * 32;
  } else if (b < 4096) {                // Wo [1024][1024]
    b -= 3072;
    in = Wo; op = WoT; K = 1024; N = 1024;
    n0 = (b & 31) * 32; k0 = (b >> 5) * 32;
  } else if (b < 12288) {               // W1 / V1 interleaved into W1V1T
    const int which = (b - 4096) >> 12;
    b = (b - 4096) & 4095;
    in = which ? V1 : W1; op = W1V1T; K = 1024; N = 4096; ilv = 1 + which;
    n0 = (b & 127) * 32; k0 = (b >> 7) * 32;
  } else {                              // W2 [4096][1024]
    b -= 12288;
    in = W2; op = W2T; K = 4096; N = 1024;
    n0 = (b & 31) * 32; k0 = (b >> 5) * 32;
  }
  const int tx = threadIdx.x & 31, ty = threadIdx.x >> 5;
  for (int i = ty; i < 32; i += 8)
    t[i][tx] = in[(size_t)(k0 + i) * N + n0 + tx];
  __syncthreads();
  for (int i = ty; i < 32; i += 8) {
    const int rn = n0 + i;
    const int r = ilv ? ((((rn >> 4) << 5) | (rn & 15)) | ((ilv - 1) << 4)) : rn;
    op[(size_t)r * K + k0 + tx] = f2bf(t[tx][i]);
  }
}

// ---------------- RMSNorm: f32 [row][1024] -> bf16 --------------------------
__global__ void rmsnorm_kernel(const float* __restrict__ in, const float* __restrict__ g,
                               u16* __restrict__ out) {
  __shared__ float psum[4];
  const int row = blockIdx.x, tid = threadIdx.x;
  const float4 x = ((const float4*)(in + (size_t)row * 1024))[tid];
  float ss = x.x * x.x + x.y * x.y + x.z * x.z + x.w * x.w;
  for (int m = 1; m < 64; m <<= 1) ss += __shfl_xor(ss, m, 64);
  if ((tid & 63) == 0) psum[tid >> 6] = ss;
  __syncthreads();
  const float tot = psum[0] + psum[1] + psum[2] + psum[3];
  const float inv = rsqrtf(tot * (1.0f / 1024.0f));
  const float4 gv = ((const float4*)g)[tid];
  u16x4 o;
  o[0] = f2bf(gv.x * x.x * inv); o[1] = f2bf(gv.y * x.y * inv);
  o[2] = f2bf(gv.z * x.z * inv); o[3] = f2bf(gv.w * x.w * inv);
  *(u16x4*)&out[(size_t)row * 1024 + tid * 4] = o;
}

// ---------------- phase-pipelined bf16 GEMM (round-6 proven schedule) --------
// BM=256: 4 phases/K-tile; P0 reads aLO + all b, P1 MFMA b23 + aHI reads at
// end, P2 stage B(t+2), P3 stage A(t+2); one barrier per phase boundary;
// vmcnt(8) at tile entry. BM=128: 2 phases, vmcnt(2).
enum { MQKV = 0, MSA = 1, MFSILU = 2, MFF2 = 3 };

template <int MODE, int BM>
__global__ __launch_bounds__(512, 2) void gemm3(
    const u16* __restrict__ A, const u16* __restrict__ Bt,
    const int K,
    u16* __restrict__ oq, u16* __restrict__ ok, u16* __restrict__ ov,
    float* __restrict__ of, const float* __restrict__ afp,
    u16* __restrict__ ob) {
  constexpr int ABUF = BM * 64;        // u16 per A buffer
  constexpr bool P4 = (BM == 256);
  constexpr int MR = BM / 32;          // per-wave mi count (8 or 4)
  constexpr int AIT = BM / 64;         // glds iters per full A stage (4 or 2)
  __shared__ u16 lds[2 * ABUF + 32768];
  const int tid = threadIdx.x;
  const int w = tid >> 6, l = tid & 63;
  const int wr = w >> 2, wc = w & 3;
  const int lane16 = l & 15, lgrp = l >> 4;

  // 2D supertile XCD mapping (bijective; concurrent window ~8 rows x 3-4 cols)
  const int bid = (int)blockIdx.x, xcd = bid & 7, seq = bid >> 3;
  int by, bx;
  if (MODE == MQKV) {            // BM=128: MT=64, NT=12, grid 768
    const int j = seq / 24, t5 = seq % 24;
    by = (xcd >> 2) * 32 + j * 8 + t5 / 3;
    bx = (xcd & 3) * 3 + t5 % 3;
  } else if (MODE == MFSILU) {   // BM=256: MT=32, NT=32, grid 1024
    by = (seq >> 5) * 8 + ((seq & 31) >> 2);
    bx = xcd * 4 + (seq & 3);
  } else {                        // BM=128: MT=64, NT=4, grid 256
    by = (xcd >> 1) * 16 + (seq >> 4) * 8 + ((seq & 15) >> 1);
    bx = (xcd & 1) * 2 + (seq & 1);
  }
  const int row0 = by * BM, col0 = bx * 256;

  auto stageA = [&](int kt, int buf) {
#pragma unroll
    for (int i = 0; i < AIT; ++i) {
      const int cc = i * 512 + tid;
      const int r = cc >> 3, j = (cc & 7) ^ (r & 7);
      gload_lds16(A + (size_t)(row0 + r) * K + kt * 64 + j * 8,
                  &lds[buf * ABUF + cc * 8]);
    }
  };
  auto stageB = [&](int kt, int buf) {
#pragma unroll
    for (int i = 0; i < 4; ++i) {
      const int cc = i * 512 + tid;
      const int r = cc >> 3, j = (cc & 7) ^ (r & 7);
      gload_lds16(Bt + (size_t)(col0 + r) * K + kt * 64 + j * 8,
                  &lds[2 * ABUF + buf * 16384 + cc * 8]);
    }
  };
  auto frofs = [&](int rrow, int ks) {
    return rrow * 64 + ((((ks << 2) + lgrp) ^ (rrow & 7)) << 3);
  };

  f32x4 zero = {0.f, 0.f, 0.f, 0.f};
  f32x4 acc[MR][4];
#pragma unroll
  for (int i = 0; i < MR; ++i)
#pragma unroll
    for (int j = 0; j < 4; ++j) acc[i][j] = zero;

  const int nkt = K >> 6;
  stageA(0, 0); stageB(0, 0); stageA(1, 1);
  if (P4) stageB(1, 1);

  for (int t = 0; t < nkt; ++t) {
    const int c = t & 1;
    if (t == nkt - 1)  asm volatile("s_waitcnt vmcnt(0)\ns_barrier" ::: "memory");
    else if (P4)       asm volatile("s_waitcnt vmcnt(8)\ns_barrier" ::: "memory");
    else               asm volatile("s_waitcnt vmcnt(2)\ns_barrier" ::: "memory");
    const u16* ap = &lds[c * ABUF];
    const u16* bp = &lds[2 * ABUF + c * 16384];
    short8 a[4][2], b01[2][2], b23[2][2];

    // ---- phase 0: ALL frag reads for P0/P1 issued here ----
    if (!P4) { if (t + 1 < nkt) stageB(t + 1, c ^ 1); }
#pragma unroll
    for (int mi = 0; mi < 4; ++mi)
#pragma unroll
      for (int ks = 0; ks < 2; ++ks)
        a[mi][ks] = *(const short8*)&ap[frofs(wr * (BM / 2) + mi * 16 + lane16, ks)];
#pragma unroll
    for (int ni = 0; ni < 2; ++ni)
#pragma unroll
      for (int ks = 0; ks < 2; ++ks) {
        b01[ni][ks] = *(const short8*)&bp[frofs(wc * 64 + ni * 16 + lane16, ks)];
        b23[ni][ks] = *(const short8*)&bp[frofs(wc * 64 + (ni + 2) * 16 + lane16, ks)];
      }
    __builtin_amdgcn_s_setprio(1);
#pragma unroll
    for (int ks = 0; ks < 2; ++ks)
#pragma unroll
      for (int mi = 0; mi < 4; ++mi)
#pragma unroll
        for (int ni = 0; ni < 2; ++ni)
          acc[mi][ni] = __builtin_amdgcn_mfma_f32_16x16x32_bf16(a[mi][ks], b01[ni][ks], acc[mi][ni], 0, 0, 0);
    __builtin_amdgcn_s_setprio(0);
    asm volatile("s_barrier" ::: "memory");

    if (P4) {
      // ---- phase 1: MFMA (aLO x b23); prefetch aHI at end (aLO dead after) ----
      __builtin_amdgcn_s_setprio(1);
#pragma unroll
      for (int ks = 0; ks < 2; ++ks)
#pragma unroll
        for (int mi = 0; mi < 4; ++mi)
#pragma unroll
          for (int ni = 0; ni < 2; ++ni)
            acc[mi][ni + 2] = __builtin_amdgcn_mfma_f32_16x16x32_bf16(a[mi][ks], b23[ni][ks], acc[mi][ni + 2], 0, 0, 0);
      __builtin_amdgcn_s_setprio(0);
#pragma unroll
      for (int mi = 0; mi < 4; ++mi)
#pragma unroll
        for (int ks = 0; ks < 2; ++ks)
          a[mi][ks] = *(const short8*)&ap[frofs(wr * 128 + (mi + 4) * 16 + lane16, ks)];
      asm volatile("s_barrier" ::: "memory");

      // ---- phase 2: stage B(t+2)->c (B(c) reads done), MFMA (aHI x b01) ----
      if (t + 2 < nkt) stageB(t + 2, c);
      __builtin_amdgcn_s_setprio(1);
#pragma unroll
      for (int ks = 0; ks < 2; ++ks)
#pragma unroll
        for (int mi = 0; mi < 4; ++mi)
#pragma unroll
          for (int ni = 0; ni < 2; ++ni)
            acc[(MR == 8 ? mi + 4 : mi)][ni] = __builtin_amdgcn_mfma_f32_16x16x32_bf16(a[mi][ks], b01[ni][ks], acc[(MR == 8 ? mi + 4 : mi)][ni], 0, 0, 0);
      __builtin_amdgcn_s_setprio(0);
      asm volatile("s_barrier" ::: "memory");

      // ---- phase 3: stage A(t+2)->c (A(c) reads done), MFMA (aHI x b23) ----
      if (t + 2 < nkt) stageA(t + 2, c);
      __builtin_amdgcn_s_setprio(1);
#pragma unroll
      for (int ks = 0; ks < 2; ++ks)
#pragma unroll
        for (int mi = 0; mi < 4; ++mi)
#pragma unroll
          for (int ni = 0; ni < 2; ++ni)
            acc[(MR == 8 ? mi + 4 : mi)][ni + 2] = __builtin_amdgcn_mfma_f32_16x16x32_bf16(a[mi][ks], b23[ni][ks], acc[(MR == 8 ? mi + 4 : mi)][ni + 2], 0, 0, 0);
      __builtin_amdgcn_s_setprio(0);
    } else {
      // ---- phase 1 (2-phase): stage A(t+2)->c, MFMA (a x b23) ----
      if (t + 2 < nkt) stageA(t + 2, c);
      __builtin_amdgcn_s_setprio(1);
#pragma unroll
      for (int ks = 0; ks < 2; ++ks)
#pragma unroll
        for (int mi = 0; mi < 4; ++mi)
#pragma unroll
          for (int ni = 0; ni < 2; ++ni)
            acc[mi][ni + 2] = __builtin_amdgcn_mfma_f32_16x16x32_bf16(a[mi][ks], b23[ni][ks], acc[mi][ni + 2], 0, 0, 0);
      __builtin_amdgcn_s_setprio(0);
    }
  }
  asm volatile("s_barrier" ::: "memory");

  // ---------------- epilogues ----------------
  if (MODE == MQKV) {
#pragma unroll
    for (int mi = 0; mi < MR; ++mi) {
      const int sbase = row0 + wr * (BM / 2) + mi * 16 + lgrp * 4;
      const int bbt = sbase >> 11, sr = sbase & 2047;
#pragma unroll
      for (int ni = 0; ni < 4; ++ni) {
        const int j = col0 + wc * 64 + ni * 16 + lane16;
        const int which = j >> 10, rr = j & 1023, h = rr >> 6, kk = rr & 63;
        const int bh = bbt * 16 + h;
        if (which == 2) {
          u16x4 pk;
#pragma unroll
          for (int r = 0; r < 4; ++r) pk[r] = f2bf(acc[mi][ni][r]);
          *(u16x4*)&ov[((size_t)bh * 64 + kk) * 2048 + sr] = pk;  // V^T [bh][dk][t]
        } else {
          u16* dst = (which == 0) ? oq : ok;
          const float scl = (which == 0) ? 0.125f : 1.0f;
#pragma unroll
          for (int r = 0; r < 4; ++r)
            dst[((size_t)bh * 2048 + sr + r) * 64 + kk] = f2bf(acc[mi][ni][r] * scl);
        }
      }
    }
  } else if (MODE == MFSILU) {
    // fused FF1: even ni fragments = h1 (W1), odd = h2 (V1); out = silu(h1)*h2
    u16* ep = &lds[w * 576];  // per-wave [16][34]
    const int orow = l >> 2, ocol = (l & 3) * 8;
#pragma unroll
    for (int mi = 0; mi < MR; ++mi) {
#pragma unroll
      for (int p = 0; p < 2; ++p)
#pragma unroll
        for (int r = 0; r < 4; ++r) {
          const float h1 = acc[mi][2 * p][r], h2 = acc[mi][2 * p + 1][r];
          ep[(lgrp * 4 + r) * 34 + p * 16 + lane16] = f2bf(h1 / (1.0f + __expf(-h1)) * h2);
        }
      short8 v = *(const short8*)&ep[orow * 34 + ocol];
      *(short8*)&ob[(size_t)(row0 + wr * (BM / 2) + mi * 16 + orow) * 4096 +
                    (col0 >> 1) + wc * 32 + ocol] = v;
    }
  } else {  // MSA / MFF2: f32 out with residual / accumulate (N = 1024)
#pragma unroll
    for (int mi = 0; mi < MR; ++mi) {
      const int row = row0 + wr * (BM / 2) + mi * 16 + lgrp * 4;
#pragma unroll
      for (int ni = 0; ni < 4; ++ni) {
        const int j = col0 + wc * 64 + ni * 16 + lane16;
#pragma unroll
        for (int r = 0; r < 4; ++r) {
          const size_t idx = (size_t)(row + r) * 1024 + j;
          const float base = (MODE == MSA) ? afp[idx] : of[idx];
          of[idx] = base + acc[mi][ni][r];
        }
      }
    }
  }
}

// ---------------- attention: 4 warps x 32 Q-rows, swapped 32x32 MFMA ---------
__global__ void attn2_kernel(const u16* __restrict__ qb, const u16* __restrict__ kb,
                             const u16* __restrict__ vT, u16* __restrict__ obuf,
                             const int* __restrict__ lens) {
  __shared__ u16 sm[9216];
  const int tid = threadIdx.x;
  const int l = tid & 63, wid = tid >> 6;
  const int l31 = l & 31, hi = l >> 5;
  const int bh = blockIdx.x, b = bh >> 4, h = bh & 15;
  const int q0 = blockIdx.y * 128;
  const int len = lens[b];

  if (q0 >= len) {
    short8 z = {0, 0, 0, 0, 0, 0, 0, 0};
#pragma unroll
    for (int c = 0; c < 4; ++c) {
      const int ck = c * 256 + tid;
      const int r = ck >> 3, j = ck & 7;
      *(short8*)&obuf[((size_t)b * 2048 + q0 + r) * 1024 + h * 64 + j * 8] = z;
    }
    return;
  }

  const int q0w = q0 + wid * 32;
  const u16* qp = qb + ((size_t)bh * 2048 + q0w + l31) * 64;
  short8 qf0 = *(const short8*)(qp + hi * 8);
  short8 qf1 = *(const short8*)(qp + 16 + hi * 8);
  short8 qf2 = *(const short8*)(qp + 32 + hi * 8);
  short8 qf3 = *(const short8*)(qp + 48 + hi * 8);

  f32x16 oa0 = {0.f,0.f,0.f,0.f,0.f,0.f,0.f,0.f,0.f,0.f,0.f,0.f,0.f,0.f,0.f,0.f};
  f32x16 oa1 = oa0;
  float m_run = -1e30f, l_run = 0.f;

  const int swz = (l31 & 7) << 3;
  const int nt = (len + 63) >> 6;
  for (int kt = 0; kt < nt; ++kt) {
    const int t0 = kt * 64;
    __syncthreads();
#pragma unroll
    for (int c = 0; c < 2; ++c) {
      const int ck = c * 256 + wid * 64 + l;
      const int r = ck >> 3;
      const int j = (ck & 7) ^ (r & 7);
      gload_lds16(kb + ((size_t)bh * 2048 + t0 + r) * 64 + j * 8,
                  &sm[(c * 256 + wid * 64) * 8]);
      gload_lds16(vT + ((size_t)bh * 64 + r) * 2048 + t0 + j * 8,
                  &sm[4096 + (c * 256 + wid * 64) * 8]);
    }
    __syncthreads();

    f32x16 sc0 = {0.f,0.f,0.f,0.f,0.f,0.f,0.f,0.f,0.f,0.f,0.f,0.f,0.f,0.f,0.f,0.f};
    f32x16 sc1 = sc0;
#pragma unroll
    for (int ds = 0; ds < 4; ++ds) {
      const int col = (ds * 16 + hi * 8) ^ swz;
      const short8 kf0 = *(const short8*)&sm[(0 + l31) * 64 + col];
      const short8 kf1 = *(const short8*)&sm[(32 + l31) * 64 + col];
      const short8 qf = (ds == 0) ? qf0 : (ds == 1) ? qf1 : (ds == 2) ? qf2 : qf3;
      sc0 = __builtin_amdgcn_mfma_f32_32x32x16_bf16(kf0, qf, sc0, 0, 0, 0);
      sc1 = __builtin_amdgcn_mfma_f32_32x32x16_bf16(kf1, qf, sc1, 0, 0, 0);
    }

    if (t0 + 64 > len) {
      const int tb = t0 + 4 * hi;
#pragma unroll
      for (int i = 0; i < 16; ++i) {
        const int tg = tb + (i & 3) + 8 * (i >> 2);
        if (tg >= len) sc0[i] = -1e30f;
        if (tg + 32 >= len) sc1[i] = -1e30f;
      }
    }

    float mt = sc0[0];
#pragma unroll
    for (int i = 1; i < 16; ++i) mt = fmaxf(mt, sc0[i]);
#pragma unroll
    for (int i = 0; i < 16; ++i) mt = fmaxf(mt, sc1[i]);
    mt = fmaxf(mt, __shfl_xor(mt, 32, 64));
    const float mnew = fmaxf(m_run, mt);
    const float fac = __expf(m_run - mnew);
    m_run = mnew;
    float sum = 0.f;
#pragma unroll
    for (int i = 0; i < 16; ++i) { sc0[i] = __expf(sc0[i] - mnew); sum += sc0[i]; }
#pragma unroll
    for (int i = 0; i < 16; ++i) { sc1[i] = __expf(sc1[i] - mnew); sum += sc1[i]; }
    sum += __shfl_xor(sum, 32, 64);
    l_run = l_run * fac + sum;
#pragma unroll
    for (int i = 0; i < 16; ++i) { oa0[i] *= fac; oa1[i] *= fac; }

    unsigned wv[16];
#pragma unroll
    for (int k = 0; k < 8; ++k) wv[k] = cvtpk(sc0[2 * k], sc0[2 * k + 1]);
#pragma unroll
    for (int k = 0; k < 8; ++k) wv[8 + k] = cvtpk(sc1[2 * k], sc1[2 * k + 1]);
    unsigned pw[16];
#pragma unroll
    for (int s = 0; s < 2; ++s) {
#pragma unroll
      for (int half = 0; half < 2; ++half) {
        const unsigned a0 = wv[8 * s + 4 * half + 0], a1 = wv[8 * s + 4 * half + 1];
        const unsigned a2 = wv[8 * s + 4 * half + 2], a3 = wv[8 * s + 4 * half + 3];
        const unsigned e0 = (unsigned)__shfl_xor((int)(hi ? a0 : a2), 32, 64);
        const unsigned e1 = (unsigned)__shfl_xor((int)(hi ? a1 : a3), 32, 64);
        const int o = s * 8 + half * 4;
        pw[o + 0] = hi ? e0 : a0;
        pw[o + 1] = hi ? e1 : a1;
        pw[o + 2] = hi ? a2 : e0;
        pw[o + 3] = hi ? a3 : e1;
      }
    }
#pragma unroll
    for (int g = 0; g < 4; ++g) {
      union { unsigned u[4]; short8 s8; } pk;
      pk.u[0] = pw[4 * g + 0]; pk.u[1] = pw[4 * g + 1];
      pk.u[2] = pw[4 * g + 2]; pk.u[3] = pw[4 * g + 3];
      const int col = (g * 16 + hi * 8) ^ swz;
      const short8 vf0 = *(const short8*)&sm[4096 + (0 + l31) * 64 + col];
      const short8 vf1 = *(const short8*)&sm[4096 + (32 + l31) * 64 + col];
      oa0 = __builtin_amdgcn_mfma_f32_32x32x16_bf16(vf0, pk.s8, oa0, 0, 0, 0);
      oa1 = __builtin_amdgcn_mfma_f32_32x32x16_bf16(vf1, pk.s8, oa1, 0, 0, 0);
    }
  }

  __syncthreads();
  const float invl = 1.0f / l_run;
  u16* ow = &sm[wid * 2304];  // per-warp [32 s][72]
#pragma unroll
  for (int i = 0; i < 16; ++i) {
    const int d0 = (i & 3) + 8 * (i >> 2) + 4 * hi;
    ow[l31 * 72 + d0] = f2bf(oa0[i] * invl);
    ow[l31 * 72 + 32 + d0] = f2bf(oa1[i] * invl);
  }
  short8 z = {0, 0, 0, 0, 0, 0, 0, 0};
#pragma unroll
  for (int c = 0; c < 4; ++c) {
    const int ck = c * 64 + l;
    const int r = ck >> 3, j = ck & 7;
    short8 v = *(const short8*)&ow[r * 72 + j * 8];
    if (q0w + r >= len) v = z;
    *(short8*)&obuf[((size_t)b * 2048 + q0w + r) * 1024 + h * 64 + j * 8] = v;
  }
}

// ---------------- launch ------------------------------------------------------
extern "C" void kernel_launch(void* const* d_in, const int* in_sizes, int n_in,
                              void* d_out, int out_size, void* d_ws, size_t ws_size,
                              hipStream_t stream) {
  const float* src = (const float*)d_in[0];
  const unsigned char* mask = (const unsigned char*)d_in[1];
  const float* Wq = (const float*)d_in[2];
  const float* Wk = (const float*)d_in[3];
  const float* Wv = (const float*)d_in[4];
  const float* Wo = (const float*)d_in[5];
  const float* g1 = (const float*)d_in[6];
  const float* g2 = (const float*)d_in[7];
  const float* W1 = (const float*)d_in[8];
  const float* V1 = (const float*)d_in[9];
  const float* W2 = (const float*)d_in[10];
  float* out = (float*)d_out;
  char* ws = (char*)d_ws;

  int* lens   = (int*)ws;
  u16* WqkvT  = (u16*)(ws + 256);        // [3072][1024]
  u16* WoT    = (u16*)(ws + 6291712);    // [1024][1024]
  u16* W1V1T  = (u16*)(ws + 8388864);    // [8192][1024] interleaved W1|V1
  u16* W2T    = (u16*)(ws + 25166080);   // [1024][4096]
  u16* xb     = (u16*)(ws + 33554688);   // [8192][1024] bf16 (x, later y)
  u16* qbf    = (u16*)(ws + 50331904);   // [64][2048][64] (pre-scaled by 1/8)
  u16* kbf    = (u16*)(ws + 67109120);   // [64][2048][64]
  u16* vTb    = (u16*)(ws + 83886336);   // [64][64][2048]
  u16* obf    = (u16*)(ws + 100663552);  // [8192][1024]
  u16* c1     = qbf;                     // [8192][4096] reuses q|k|vT|o region

  compute_lens<<<1, 256, 0, stream>>>(mask, lens);
  convT_all<<<16384, 256, 0, stream>>>(Wq, Wk, Wv, Wo, W1, V1, W2,
                                       WqkvT, WoT, W1V1T, W2T);

  rmsnorm_kernel<<<8192, 256, 0, stream>>>(src, g1, xb);
  gemm3<MQKV, 128><<<768, 512, 0, stream>>>(xb, WqkvT, 1024,
                                            qbf, kbf, vTb, nullptr, nullptr, nullptr);
  attn2_kernel<<<dim3(64, 16), 256, 0, stream>>>(qbf, kbf, vTb, obf, lens);
  gemm3<MSA, 128><<<256, 512, 0, stream>>>(obf, WoT, 1024,
                                           nullptr, nullptr, nullptr, out, src, nullptr);
  rmsnorm_kernel<<<8192, 256, 0, stream>>>(out, g2, xb);
  gemm3<MFSILU, 256><<<1024, 512, 0, stream>>>(xb, W1V1T, 1024,
                                               nullptr, nullptr, nullptr, nullptr, nullptr, c1);
  gemm3<MFF2, 128><<<256, 512, 0, stream>>>(c1, W2T, 4096,
                                            nullptr, nullptr, nullptr, out, nullptr, nullptr);
}